// Round 10
// baseline (40.245 us; speedup 1.0000x reference)
//
#include <hip/hip_runtime.h>
#include <hip/hip_bf16.h>

#define D_IN  128
#define D_HID 256
#define NB_A  256
#define NT_A  512
#define NBLK  256
#define NTHR  512
#define MAXG  512
#define HASHN 2048
#define PBM_STRIDE 72

// ws int layout:
//  [0..7]     barrier slots (zeroed by A block 0)
//  [32..544]  per-unique-node degree sums (u=0 agent), zeroed by A, atomicAdd by BC
//  [1024..]   per-A-block match regions (NB_A x PBM_STRIDE)
//  floats:    [24576]=h0[256], [25088]=h1raw[256], [25600]=h2raw[256]
#define OFF_BAR  0
#define OFF_DEG  32
#define OFF_PBM  1024
#define OFF_H0   24576
#define OFF_H1   25088
#define OFF_H2   25600

#define ALD(p)   __hip_atomic_load((p),      __ATOMIC_RELAXED, __HIP_MEMORY_SCOPE_AGENT)
#define AST(p,v) __hip_atomic_store((p),(v), __ATOMIC_RELAXED, __HIP_MEMORY_SCOPE_AGENT)

__device__ __forceinline__ float ldf(const void* p, long long i, bool b16) {
    if (b16) {
        unsigned short u = ((const unsigned short*)p)[i];
        return __uint_as_float(((unsigned int)u) << 16);
    }
    return ((const float*)p)[i];
}

__device__ __forceinline__ unsigned hash_n(int key) {
    return (((unsigned)key * 2654435761u) >> 21) & (HASHN - 1);
}

__device__ __forceinline__ int detect_i64(const void* edges, int tid, int* s) {
    if (tid < 64) {
        const unsigned* w = (const unsigned*)edges;
        unsigned long long b = __ballot(w[2 * tid + 1] == 0u);
        if (tid == 0) *s = (b == ~0ULL) ? 1 : 0;
    }
    __syncthreads();
    return *s;
}

__device__ __forceinline__ int detect_b16(const void* state, int tid, int* s) {
    if (tid < 64) {
        const unsigned short* p = (const unsigned short*)state;
        unsigned short v = p[tid];
        int e = (v >> 7) & 0xff;
        unsigned long long b = __ballot(v == 0 || (e >= 90 && e <= 140));
        if (tid == 0) *s = (b == ~0ULL) ? 1 : 0;
    }
    __syncthreads();
    return *s;
}

// co-resident barrier: cheap arrival (one ACQ-free add), RELAXED spin by the
// (few) waiters, single fence on exit. R8 lesson: never spin with 256 waiters.
__device__ __forceinline__ void grid_bar(int* slot, int cnt, bool wait) {
    __syncthreads();
    if (threadIdx.x == 0) {
        __threadfence();
        __hip_atomic_fetch_add(slot, 1, __ATOMIC_RELEASE, __HIP_MEMORY_SCOPE_AGENT);
        if (wait) {
            while (__hip_atomic_load(slot, __ATOMIC_RELAXED, __HIP_MEMORY_SCOPE_AGENT) < cnt)
                __builtin_amdgcn_s_sleep(2);
            __threadfence();
        }
    }
    __syncthreads();
}

// A: zero control state (block 0) + vectorized match scan + weight L3-prefetch.
__global__ void __launch_bounds__(NT_A) k_A(const void* edges, const void* state,
                                            const int* agent_p,
                                            const void* w0, const void* w1,
                                            const void* w2, const void* w3,
                                            int* wsi, long long n_edges) {
    __shared__ int s_pref[NT_A];
    __shared__ int s_list[64];
    __shared__ int s_i64, s_b16;
    int tid = threadIdx.x, bid = blockIdx.x;
    int i64 = detect_i64(edges, tid, &s_i64);
    int b16 = detect_b16(state, tid, &s_b16);

    if (bid == 0) {
        if (tid < 8) AST(&wsi[OFF_BAR + tid], 0);
        for (int i = tid; i <= MAXG; i += NT_A) AST(&wsi[OFF_DEG + i], 0);
    }

    // prefetch weights into L3: one dword per 64B line, spread over the grid
    {
        int esz = b16 ? 2 : 4;
        long long gt = (long long)bid * NT_A + tid;
        const void* arr[4] = { w0, w1, w2, w3 };
        const int elems[4] = { D_IN * D_HID, D_HID * D_HID, D_HID * D_HID, D_HID * 8 };
        long long base = 0;
        #pragma unroll
        for (int a = 0; a < 4; a++) {
            long long lines = ((long long)elems[a] * esz) >> 6;
            long long idx = gt - base;
            if (idx >= 0 && idx < lines) {
                unsigned v = *(const unsigned*)((const char*)arr[a] + (idx << 6));
                asm volatile("" :: "v"(v));
            }
            base += lines;
        }
    }

    int agent = agent_p[0];
    long long base4 = ((long long)bid * NT_A + tid) * 4;
    const long long stride4 = (long long)NB_A * NT_A * 4;
    long long nv = n_edges & ~3LL;
    int c = 0;
    if (i64) {
        const long long* dst = (const long long*)edges + n_edges;
        for (long long e = base4; e < nv; e += stride4) {
            long2 a = *(const long2*)(dst + e);
            long2 b = *(const long2*)(dst + e + 2);
            c += ((int)a.x == agent) + ((int)a.y == agent)
               + ((int)b.x == agent) + ((int)b.y == agent);
        }
        if (bid == 0 && tid == 0)
            for (long long e = nv; e < n_edges; e++) c += ((int)dst[e] == agent);
    } else {
        const int* dst = (const int*)edges + n_edges;
        for (long long e = base4; e < nv; e += stride4) {
            int4 a = *(const int4*)(dst + e);
            c += (a.x == agent) + (a.y == agent) + (a.z == agent) + (a.w == agent);
        }
        if (bid == 0 && tid == 0)
            for (long long e = nv; e < n_edges; e++) c += (dst[e] == agent);
    }
    s_pref[tid] = c;
    __syncthreads();
    #pragma unroll
    for (int off = 1; off < NT_A; off <<= 1) {
        int v = (tid >= off) ? s_pref[tid - off] : 0;
        __syncthreads();
        s_pref[tid] += v;
        __syncthreads();
    }
    int excl = s_pref[tid] - c;
    int total = s_pref[NT_A - 1];
    if (c > 0 && excl < 64) {
        int k = excl;
        if (i64) {
            const long long* src = (const long long*)edges;
            const long long* dst = src + n_edges;
            for (long long e = base4; e < nv; e += stride4) {
                long2 a = *(const long2*)(dst + e);
                long2 b = *(const long2*)(dst + e + 2);
                if ((int)a.x == agent) { if (k < 64) s_list[k] = (int)src[e];     k++; }
                if ((int)a.y == agent) { if (k < 64) s_list[k] = (int)src[e + 1]; k++; }
                if ((int)b.x == agent) { if (k < 64) s_list[k] = (int)src[e + 2]; k++; }
                if ((int)b.y == agent) { if (k < 64) s_list[k] = (int)src[e + 3]; k++; }
            }
            if (bid == 0 && tid == 0)
                for (long long e = nv; e < n_edges; e++)
                    if ((int)dst[e] == agent) { if (k < 64) s_list[k] = (int)src[e]; k++; }
        } else {
            const int* src = (const int*)edges;
            const int* dst = src + n_edges;
            for (long long e = base4; e < nv; e += stride4) {
                int4 a = *(const int4*)(dst + e);
                if (a.x == agent) { if (k < 64) s_list[k] = src[e];     k++; }
                if (a.y == agent) { if (k < 64) s_list[k] = src[e + 1]; k++; }
                if (a.z == agent) { if (k < 64) s_list[k] = src[e + 2]; k++; }
                if (a.w == agent) { if (k < 64) s_list[k] = src[e + 3]; k++; }
            }
            if (bid == 0 && tid == 0)
                for (long long e = nv; e < n_edges; e++)
                    if (dst[e] == agent) { if (k < 64) s_list[k] = src[e]; k++; }
        }
    }
    __syncthreads();
    int* reg = wsi + OFF_PBM + bid * PBM_STRIDE;
    int tw = total < 64 ? total : 64;
    if (tid == 0) reg[0] = tw;
    if (tid < tw) reg[1 + tid] = s_list[tid];
}

__device__ __forceinline__ float ln256(float v, const void* lnw, const void* lnb,
                                       float* s_red, int tid, bool b16) {
    if (tid < 256) {
        float x = v;
        #pragma unroll
        for (int o = 32; o > 0; o >>= 1) x += __shfl_down(x, o);
        if ((tid & 63) == 0) s_red[tid >> 6] = x;
    }
    __syncthreads();
    float mu = (s_red[0] + s_red[1] + s_red[2] + s_red[3]) * (1.0f / 256.0f);
    if (tid < 256) {
        float dd = v - mu;
        float x = dd * dd;
        #pragma unroll
        for (int o = 32; o > 0; o >>= 1) x += __shfl_down(x, o);
        if ((tid & 63) == 0) s_red[4 + (tid >> 6)] = x;
    }
    __syncthreads();
    float var = (s_red[4] + s_red[5] + s_red[6] + s_red[7]) * (1.0f / 256.0f);
    float y = 0.0f;
    if (tid < 256)
        y = fmaxf((v - mu) * rsqrtf(var + 1e-5f) * ldf(lnw, tid, b16) + ldf(lnb, tid, b16), 0.0f);
    __syncthreads();
    return y;
}

// BC: 256 blocks. Phase B (all): rebuild match list + LDS hash + vectorized
// degree count -> global DEG. One barrier (256 arrivals, 25 spinners).
// Phase C (blocks 0..24): MLP pipeline, match list/hash kept in LDS.
__global__ void __launch_bounds__(NTHR) k_BC(
    const void* state, const void* edges, const int* agent_p,
    const void* conv_w, const void* conv_b,
    const void* fc1_w, const void* fc1_b, const void* ln1_w, const void* ln1_b,
    const void* fc2_w, const void* fc2_b, const void* ln2_w, const void* ln2_b,
    const void* mu_w, const void* mu_b,
    int* wsi, long long n_edges, void* out)
{
    __shared__ int   s_pref[NTHR];
    __shared__ int   s_nodes[MAXG + 1];
    __shared__ int   s_hkey[HASHN];
    __shared__ int   s_hval[HASHN];
    __shared__ int   s_cnt[MAXG + 1];
    __shared__ float s_in[D_HID];
    __shared__ float s_part[NTHR];
    __shared__ float s_xs[D_IN];
    __shared__ float s_red[8];
    __shared__ float s_w[MAXG];
    __shared__ int   s_i64, s_b16, s_nu;

    int tid = threadIdx.x, bid = blockIdx.x;
    int i64 = detect_i64(edges, tid, &s_i64);
    bool b16 = detect_b16(state, tid, &s_b16) != 0;
    float* wsf = (float*)wsi;
    int* bar = wsi + OFF_BAR;
    int agent = agent_p[0];

    // ---- Phase B: rebuild compact match list from k_A's per-block regions ----
    int bc = 0;
    if (tid < NB_A) {
        bc = wsi[OFF_PBM + tid * PBM_STRIDE];
        bc = bc < 64 ? (bc < 0 ? 0 : bc) : 64;
    }
    s_pref[tid] = bc;
    __syncthreads();
    #pragma unroll
    for (int off = 1; off < NTHR; off <<= 1) {
        int v = (tid >= off) ? s_pref[tid - off] : 0;
        __syncthreads();
        s_pref[tid] += v;
        __syncthreads();
    }
    int excl = s_pref[tid] - bc;
    int mc = s_pref[NTHR - 1];
    int m = mc < MAXG ? mc : MAXG;
    if (tid < NB_A) {
        for (int i = 0; i < bc; i++) {
            int g = excl + i;
            if (g < MAXG) s_nodes[1 + g] = wsi[OFF_PBM + tid * PBM_STRIDE + 1 + i];
        }
    }
    if (tid == 0) s_nodes[0] = agent;
    for (int i = tid; i < HASHN; i += NTHR) s_hkey[i] = -1;
    for (int i = tid; i <= m; i += NTHR) s_cnt[i] = 0;
    __syncthreads();

    // deterministic serial hash insert (agent first -> u=0); duplicates share u
    if (tid == 0) {
        int nu = 0;
        for (int j = 0; j <= m; j++) {
            int key = s_nodes[j];
            unsigned h = hash_n(key);
            while (true) {
                if (s_hkey[h] == -1) { s_hkey[h] = key; s_hval[h] = nu++; break; }
                if (s_hkey[h] == key) break;
                h = (h + 1) & (HASHN - 1);
            }
        }
        s_nu = nu;
    }
    __syncthreads();

    // conv blocks: prefetch needed state rows (overlaps with degree count)
    if (bid < 8) {
        int esz = b16 ? 2 : 4;
        int chunks = (D_IN * esz) >> 6;
        for (int i = tid; i < (m + 1) * chunks; i += NTHR) {
            int j = i / chunks, ch = i - j * chunks;
            long long row = s_nodes[j];
            unsigned v = *(const unsigned*)((const char*)state + row * D_IN * esz + ch * 64);
            asm volatile("" :: "v"(v));
        }
    }

    // vectorized degree count over this block's slice (dst L3-warm from k_A)
    auto probe = [&](int d) {
        unsigned h = hash_n(d);
        while (true) {
            int k = s_hkey[h];
            if (k == -1) break;
            if (k == d) { atomicAdd(&s_cnt[s_hval[h]], 1); break; }
            h = (h + 1) & (HASHN - 1);
        }
    };
    long long base4 = ((long long)bid * NTHR + tid) * 4;
    const long long stride4 = (long long)NBLK * NTHR * 4;
    long long nv = n_edges & ~3LL;
    if (i64) {
        const long long* dst = (const long long*)edges + n_edges;
        for (long long e = base4; e < nv; e += stride4) {
            long2 a = *(const long2*)(dst + e);
            long2 b = *(const long2*)(dst + e + 2);
            probe((int)a.x); probe((int)a.y); probe((int)b.x); probe((int)b.y);
        }
        if (bid == 0 && tid == 0)
            for (long long e = nv; e < n_edges; e++) probe((int)dst[e]);
    } else {
        const int* dst = (const int*)edges + n_edges;
        for (long long e = base4; e < nv; e += stride4) {
            int4 a = *(const int4*)(dst + e);
            probe(a.x); probe(a.y); probe(a.z); probe(a.w);
        }
        if (bid == 0 && tid == 0)
            for (long long e = nv; e < n_edges; e++) probe(dst[e]);
    }
    __syncthreads();
    for (int i = tid; i < s_nu; i += NTHR)
        if (s_cnt[i]) atomicAdd(&wsi[OFF_DEG + i], s_cnt[i]);

    // 256 arrivals, only blocks 0..24 spin (R8 lesson: few spinners only)
    grid_bar(&bar[0], NBLK, bid < 25);
    if (bid >= 25) return;

    // ---- Phase C / conv blocks 0..7: gather + conv matvec slice -> H0 ----
    if (bid < 8) {
        float dinv_a = rsqrtf((float)(ALD(&wsi[OFF_DEG]) + 1));
        for (int i = tid; i < m; i += NTHR) {
            int key = s_nodes[1 + i];
            unsigned h = hash_n(key);
            while (s_hkey[h] != key) h = (h + 1) & (HASHN - 1);
            s_w[i] = dinv_a * rsqrtf((float)(ALD(&wsi[OFF_DEG + s_hval[h]]) + 1));
        }
        __syncthreads();
        int d = tid & 127, jg = tid >> 7;   // 4 j-groups x 128 dims
        float acc = (jg == 0) ? dinv_a * dinv_a * ldf(state, (long long)agent * D_IN + d, b16) : 0.0f;
        for (int j = jg; j < m; j += 4)
            acc += s_w[j] * ldf(state, (long long)s_nodes[1 + j] * D_IN + d, b16);
        s_part[tid] = acc;
        __syncthreads();
        if (tid < D_IN)
            s_xs[tid] = s_part[tid] + s_part[tid + 128] + s_part[tid + 256] + s_part[tid + 384];
        __syncthreads();
        int o = bid * 32 + (tid & 31), ks = tid >> 5;   // 16 k-slices of 8
        float a = 0.0f;
        #pragma unroll 8
        for (int k = ks * 8; k < ks * 8 + 8; k++)
            a += s_xs[k] * ldf(conv_w, (long long)k * D_HID + o, b16);
        s_part[tid] = a;
        __syncthreads();
        if (tid < 32) {
            int oo = bid * 32 + tid;
            float h = ldf(conv_b, oo, b16);
            #pragma unroll
            for (int s2 = 0; s2 < 16; s2++) h += s_part[s2 * 32 + tid];
            AST(&wsf[OFF_H0 + oo], fmaxf(h, 0.0f));
        }
    }
    grid_bar(&bar[1], 25, bid >= 8 && bid < 16);
    if (bid < 8) return;

    // ---- fc1 blocks 8..15 -> h1raw ----
    if (bid < 16) {
        if (tid < D_HID) s_in[tid] = ALD(&wsf[OFF_H0 + tid]);
        __syncthreads();
        int o = (bid - 8) * 32 + (tid & 31), ks = tid >> 5;   // 16 slices x 16 k
        float a = 0.0f;
        #pragma unroll 8
        for (int k = ks * 16; k < ks * 16 + 16; k++)
            a += s_in[k] * ldf(fc1_w, (long long)k * D_HID + o, b16);
        s_part[tid] = a;
        __syncthreads();
        if (tid < 32) {
            int oo = (bid - 8) * 32 + tid;
            float h = ldf(fc1_b, oo, b16);
            #pragma unroll
            for (int s2 = 0; s2 < 16; s2++) h += s_part[s2 * 32 + tid];
            AST(&wsf[OFF_H1 + oo], h);
        }
    }
    grid_bar(&bar[2], 17, bid >= 16 && bid < 24);
    if (bid < 16) return;

    // ---- fc2 blocks 16..23 — LN1+relu inline -> h2raw ----
    if (bid < 24) {
        float v = (tid < D_HID) ? ALD(&wsf[OFF_H1 + tid]) : 0.0f;
        float y = ln256(v, ln1_w, ln1_b, s_red, tid, b16);
        if (tid < D_HID) s_in[tid] = y;
        __syncthreads();
        int o = (bid - 16) * 32 + (tid & 31), ks = tid >> 5;
        float a = 0.0f;
        #pragma unroll 8
        for (int k = ks * 16; k < ks * 16 + 16; k++)
            a += s_in[k] * ldf(fc2_w, (long long)k * D_HID + o, b16);
        s_part[tid] = a;
        __syncthreads();
        if (tid < 32) {
            int oo = (bid - 16) * 32 + tid;
            float h = ldf(fc2_b, oo, b16);
            #pragma unroll
            for (int s2 = 0; s2 < 16; s2++) h += s_part[s2 * 32 + tid];
            AST(&wsf[OFF_H2 + oo], h);
        }
    }
    grid_bar(&bar[3], 9, bid == 24);
    if (bid < 24) return;

    // ---- mu block 24 — LN2+relu inline, 256x8 matvec, sigmoid ----
    {
        float v = (tid < D_HID) ? ALD(&wsf[OFF_H2 + tid]) : 0.0f;
        float y = ln256(v, ln2_w, ln2_b, s_red, tid, b16);
        if (tid < D_HID) s_in[tid] = y;
        __syncthreads();
        int o = tid & 7, ks = tid >> 3;   // 64 slices x 4 k
        float a = 0.0f;
        #pragma unroll
        for (int k = ks * 4; k < ks * 4 + 4; k++)
            a += s_in[k] * ldf(mu_w, (long long)k * 8 + o, b16);
        s_part[tid] = a;
        __syncthreads();
        if (tid < 8) {
            float acc = ldf(mu_b, tid, b16);
            #pragma unroll
            for (int s2 = 0; s2 < 64; s2++) acc += s_part[s2 * 8 + tid];
            float r = 1.0f / (1.0f + expf(-acc));
            if (b16) ((__hip_bfloat16*)out)[tid] = __float2bfloat16(r);
            else     ((float*)out)[tid] = r;
        }
    }
}

extern "C" void kernel_launch(void* const* d_in, const int* in_sizes, int n_in,
                              void* d_out, int out_size, void* d_ws, size_t ws_size,
                              hipStream_t stream) {
    const void* state = d_in[0];
    const void* edges = d_in[1];
    const int* agent = (const int*)d_in[2];
    int* wsi = (int*)d_ws;
    long long n_edges = in_sizes[1] / 2;

    k_A<<<NB_A, NT_A, 0, stream>>>(edges, state, agent,
                                   d_in[3], d_in[5], d_in[9], d_in[13],
                                   wsi, n_edges);
    k_BC<<<NBLK, NTHR, 0, stream>>>(state, edges, agent,
                                    d_in[3], d_in[4],
                                    d_in[5], d_in[6], d_in[7], d_in[8],
                                    d_in[9], d_in[10], d_in[11], d_in[12],
                                    d_in[13], d_in[14],
                                    wsi, n_edges, d_out);
}

// Round 11
// 35.964 us; speedup vs baseline: 1.1190x; 1.1190x over previous
//
#include <hip/hip_runtime.h>
#include <hip/hip_bf16.h>

#define D_IN  128
#define D_HID 256
#define NB_A  256
#define NT_A  512
#define NB_B  256
#define NT_B  512
#define NT_C  512
#define MAXG  512
#define HASHN 2048
#define PBM_STRIDE 72

// ws int layout:
//  [0..7]     barrier slots for kernel C (zeroed by A block 0)
//  [16]       m (compact match count, written by B block 0)
//  [32..544]  per-unique-node degree sums (u=0 agent), zeroed by A, atomicAdd by B
//  [1024..]   per-A-block match regions (NB_A x PBM_STRIDE)
//  [20480..]  compact match src list (MAXG)
//  [21504..]  map j -> unique index u (MAXG+1 entries, j=0 is agent)
//  floats:    [24576]=h0[256], [25088]=h1raw[256], [25600]=h2raw[256]
#define OFF_BAR  0
#define OFF_M    16
#define OFF_DEG  32
#define OFF_PBM  1024
#define OFF_CM   20480
#define OFF_MAP  21504
#define OFF_H0   24576
#define OFF_H1   25088
#define OFF_H2   25600

#define ALD(p)   __hip_atomic_load((p),      __ATOMIC_RELAXED, __HIP_MEMORY_SCOPE_AGENT)
#define AST(p,v) __hip_atomic_store((p),(v), __ATOMIC_RELAXED, __HIP_MEMORY_SCOPE_AGENT)

__device__ __forceinline__ float ldf(const void* p, long long i, bool b16) {
    if (b16) {
        unsigned short u = ((const unsigned short*)p)[i];
        return __uint_as_float(((unsigned int)u) << 16);
    }
    return ((const float*)p)[i];
}

__device__ __forceinline__ unsigned hash_n(int key) {
    return (((unsigned)key * 2654435761u) >> 21) & (HASHN - 1);
}

__device__ __forceinline__ int detect_i64(const void* edges, int tid, int* s) {
    if (tid < 64) {
        const unsigned* w = (const unsigned*)edges;
        unsigned long long b = __ballot(w[2 * tid + 1] == 0u);
        if (tid == 0) *s = (b == ~0ULL) ? 1 : 0;
    }
    __syncthreads();
    return *s;
}

__device__ __forceinline__ int detect_b16(const void* state, int tid, int* s) {
    if (tid < 64) {
        const unsigned short* p = (const unsigned short*)state;
        unsigned short v = p[tid];
        int e = (v >> 7) & 0xff;
        unsigned long long b = __ballot(v == 0 || (e >= 90 && e <= 140));
        if (tid == 0) *s = (b == ~0ULL) ? 1 : 0;
    }
    __syncthreads();
    return *s;
}

// producer-side arrival: one fenced RELEASE add, no spin.
__device__ __forceinline__ void bar_arrive(int* slot) {
    __syncthreads();
    if (threadIdx.x == 0) {
        __threadfence();
        __hip_atomic_fetch_add(slot, 1, __ATOMIC_RELEASE, __HIP_MEMORY_SCOPE_AGENT);
    }
}

// consumer-side wait: RELAXED spin (R8 lesson: no acquire polling), fence on exit.
__device__ __forceinline__ void bar_wait(int* slot, int cnt) {
    if (threadIdx.x == 0) {
        while (__hip_atomic_load(slot, __ATOMIC_RELAXED, __HIP_MEMORY_SCOPE_AGENT) < cnt)
            __builtin_amdgcn_s_sleep(2);
        __threadfence();
    }
    __syncthreads();
}

// A: zero control state (block 0) + 8-wide match scan + weight L3-prefetch.
__global__ void __launch_bounds__(NT_A) k_A(const void* edges, const void* state,
                                            const int* agent_p,
                                            const void* w0, const void* w1,
                                            const void* w2, const void* w3,
                                            int* wsi, long long n_edges) {
    __shared__ int s_pref[NT_A];
    __shared__ int s_list[64];
    __shared__ int s_i64, s_b16;
    int tid = threadIdx.x, bid = blockIdx.x;
    int i64 = detect_i64(edges, tid, &s_i64);
    int b16 = detect_b16(state, tid, &s_b16);

    if (bid == 0) {
        if (tid < 8) AST(&wsi[OFF_BAR + tid], 0);
        for (int i = tid; i <= MAXG; i += NT_A) AST(&wsi[OFF_DEG + i], 0);
    }

    // prefetch weights into L3: one dword per 64B line, spread over the grid
    {
        int esz = b16 ? 2 : 4;
        long long gt = (long long)bid * NT_A + tid;
        const void* arr[4] = { w0, w1, w2, w3 };
        const int elems[4] = { D_IN * D_HID, D_HID * D_HID, D_HID * D_HID, D_HID * 8 };
        long long base = 0;
        #pragma unroll
        for (int a = 0; a < 4; a++) {
            long long lines = ((long long)elems[a] * esz) >> 6;
            long long idx = gt - base;
            if (idx >= 0 && idx < lines) {
                unsigned v = *(const unsigned*)((const char*)arr[a] + (idx << 6));
                asm volatile("" :: "v"(v));
            }
            base += lines;
        }
    }

    int agent = agent_p[0];
    long long base8 = ((long long)bid * NT_A + tid) * 8;
    const long long stride8 = (long long)NB_A * NT_A * 8;
    long long nv = n_edges & ~7LL;
    int c = 0;
    if (i64) {
        const long long* dst = (const long long*)edges + n_edges;
        for (long long e = base8; e < nv; e += stride8) {
            long2 a0 = *(const long2*)(dst + e);
            long2 a1 = *(const long2*)(dst + e + 2);
            long2 a2 = *(const long2*)(dst + e + 4);
            long2 a3 = *(const long2*)(dst + e + 6);
            c += ((int)a0.x == agent) + ((int)a0.y == agent)
               + ((int)a1.x == agent) + ((int)a1.y == agent)
               + ((int)a2.x == agent) + ((int)a2.y == agent)
               + ((int)a3.x == agent) + ((int)a3.y == agent);
        }
        if (bid == 0 && tid == 0)
            for (long long e = nv; e < n_edges; e++) c += ((int)dst[e] == agent);
    } else {
        const int* dst = (const int*)edges + n_edges;
        for (long long e = base8; e < nv; e += stride8) {
            int4 a = *(const int4*)(dst + e);
            int4 b = *(const int4*)(dst + e + 4);
            c += (a.x == agent) + (a.y == agent) + (a.z == agent) + (a.w == agent)
               + (b.x == agent) + (b.y == agent) + (b.z == agent) + (b.w == agent);
        }
        if (bid == 0 && tid == 0)
            for (long long e = nv; e < n_edges; e++) c += (dst[e] == agent);
    }
    s_pref[tid] = c;
    __syncthreads();
    #pragma unroll
    for (int off = 1; off < NT_A; off <<= 1) {
        int v = (tid >= off) ? s_pref[tid - off] : 0;
        __syncthreads();
        s_pref[tid] += v;
        __syncthreads();
    }
    int excl = s_pref[tid] - c;
    int total = s_pref[NT_A - 1];
    if (c > 0 && excl < 64) {
        int k = excl;
        if (i64) {
            const long long* src = (const long long*)edges;
            const long long* dst = src + n_edges;
            for (long long e = base8; e < nv; e += stride8) {
                #pragma unroll
                for (int q = 0; q < 8; q++) {
                    if ((int)dst[e + q] == agent) { if (k < 64) s_list[k] = (int)src[e + q]; k++; }
                }
            }
            if (bid == 0 && tid == 0)
                for (long long e = nv; e < n_edges; e++)
                    if ((int)dst[e] == agent) { if (k < 64) s_list[k] = (int)src[e]; k++; }
        } else {
            const int* src = (const int*)edges;
            const int* dst = src + n_edges;
            for (long long e = base8; e < nv; e += stride8) {
                #pragma unroll
                for (int q = 0; q < 8; q++) {
                    if (dst[e + q] == agent) { if (k < 64) s_list[k] = src[e + q]; k++; }
                }
            }
            if (bid == 0 && tid == 0)
                for (long long e = nv; e < n_edges; e++)
                    if (dst[e] == agent) { if (k < 64) s_list[k] = src[e]; k++; }
        }
    }
    __syncthreads();
    int* reg = wsi + OFF_PBM + bid * PBM_STRIDE;
    int tw = total < 64 ? total : 64;
    if (tid == 0) reg[0] = tw;
    if (tid < tw) reg[1 + tid] = s_list[tid];
}

// B: rebuild compact match list, LDS hash of unique nodes, 8-wide degree count,
// export per-unique counts + compact list + j->u map.
__global__ void __launch_bounds__(NT_B) k_B(const void* edges, const int* agent_p,
                                            int* wsi, long long n_edges) {
    __shared__ int s_pref[NT_B];
    __shared__ int s_nodes[MAXG + 1];
    __shared__ int s_hkey[HASHN];
    __shared__ int s_hval[HASHN];
    __shared__ int s_cnt[MAXG + 1];
    __shared__ int s_i64, s_nu;
    int tid = threadIdx.x, bid = blockIdx.x;
    int i64 = detect_i64(edges, tid, &s_i64);

    int bc = 0;
    if (tid < NB_A) {
        bc = wsi[OFF_PBM + tid * PBM_STRIDE];
        bc = bc < 64 ? (bc < 0 ? 0 : bc) : 64;
    }
    s_pref[tid] = bc;
    __syncthreads();
    #pragma unroll
    for (int off = 1; off < NT_B; off <<= 1) {
        int v = (tid >= off) ? s_pref[tid - off] : 0;
        __syncthreads();
        s_pref[tid] += v;
        __syncthreads();
    }
    int excl = s_pref[tid] - bc;
    int mc = s_pref[NT_B - 1];
    int m = mc < MAXG ? mc : MAXG;
    if (tid < NB_A) {
        for (int i = 0; i < bc; i++) {
            int g = excl + i;
            if (g < MAXG) s_nodes[1 + g] = wsi[OFF_PBM + tid * PBM_STRIDE + 1 + i];
        }
    }
    if (tid == 0) s_nodes[0] = agent_p[0];
    for (int i = tid; i < HASHN; i += NT_B) s_hkey[i] = -1;
    for (int i = tid; i <= m; i += NT_B) s_cnt[i] = 0;
    __syncthreads();

    if (tid == 0) {
        int nu = 0;
        for (int j = 0; j <= m; j++) {
            int key = s_nodes[j];
            unsigned h = hash_n(key);
            while (true) {
                if (s_hkey[h] == -1) { s_hkey[h] = key; s_hval[h] = nu++; break; }
                if (s_hkey[h] == key) break;
                h = (h + 1) & (HASHN - 1);
            }
        }
        s_nu = nu;
    }
    __syncthreads();

    auto probe = [&](int d) {
        unsigned h = hash_n(d);
        while (true) {
            int k = s_hkey[h];
            if (k == -1) break;
            if (k == d) { atomicAdd(&s_cnt[s_hval[h]], 1); break; }
            h = (h + 1) & (HASHN - 1);
        }
    };

    long long base8 = ((long long)bid * NT_B + tid) * 8;
    const long long stride8 = (long long)NB_B * NT_B * 8;
    long long nv = n_edges & ~7LL;
    if (i64) {
        const long long* dst = (const long long*)edges + n_edges;
        for (long long e = base8; e < nv; e += stride8) {
            long2 a0 = *(const long2*)(dst + e);
            long2 a1 = *(const long2*)(dst + e + 2);
            long2 a2 = *(const long2*)(dst + e + 4);
            long2 a3 = *(const long2*)(dst + e + 6);
            probe((int)a0.x); probe((int)a0.y); probe((int)a1.x); probe((int)a1.y);
            probe((int)a2.x); probe((int)a2.y); probe((int)a3.x); probe((int)a3.y);
        }
        if (bid == 0 && tid == 0)
            for (long long e = nv; e < n_edges; e++) probe((int)dst[e]);
    } else {
        const int* dst = (const int*)edges + n_edges;
        for (long long e = base8; e < nv; e += stride8) {
            int4 a = *(const int4*)(dst + e);
            int4 b = *(const int4*)(dst + e + 4);
            probe(a.x); probe(a.y); probe(a.z); probe(a.w);
            probe(b.x); probe(b.y); probe(b.z); probe(b.w);
        }
        if (bid == 0 && tid == 0)
            for (long long e = nv; e < n_edges; e++) probe(dst[e]);
    }
    __syncthreads();
    int nu = s_nu;
    for (int i = tid; i < nu; i += NT_B)
        if (s_cnt[i]) atomicAdd(&wsi[OFF_DEG + i], s_cnt[i]);
    if (bid == 0) {
        if (tid == 0) wsi[OFF_M] = m;
        for (int i = tid; i < m; i += NT_B) wsi[OFF_CM + i] = s_nodes[1 + i];
        for (int j = tid; j <= m; j += NT_B) {
            int key = s_nodes[j];
            unsigned h = hash_n(key);
            while (s_hkey[h] != key) h = (h + 1) & (HASHN - 1);
            wsi[OFF_MAP + j] = s_hval[h];
        }
    }
}

__device__ __forceinline__ float ln256(float v, const void* lnw, const void* lnb,
                                       float* s_red, int tid, bool b16) {
    if (tid < 256) {
        float x = v;
        #pragma unroll
        for (int o = 32; o > 0; o >>= 1) x += __shfl_down(x, o);
        if ((tid & 63) == 0) s_red[tid >> 6] = x;
    }
    __syncthreads();
    float mu = (s_red[0] + s_red[1] + s_red[2] + s_red[3]) * (1.0f / 256.0f);
    if (tid < 256) {
        float dd = v - mu;
        float x = dd * dd;
        #pragma unroll
        for (int o = 32; o > 0; o >>= 1) x += __shfl_down(x, o);
        if ((tid & 63) == 0) s_red[4 + (tid >> 6)] = x;
    }
    __syncthreads();
    float var = (s_red[4] + s_red[5] + s_red[6] + s_red[7]) * (1.0f / 256.0f);
    float y = 0.0f;
    if (tid < 256)
        y = fmaxf((v - mu) * rsqrtf(var + 1e-5f) * ldf(lnw, tid, b16) + ldf(lnb, tid, b16), 0.0f);
    __syncthreads();
    return y;
}

// C: 25-block MLP pipeline. Each block PRELOADS its weight slice into LDS
// before waiting, so post-barrier matvecs are LDS-fed. Producer-only barriers:
// slot0: conv arrivals (8). slot1: fc1 (8). slot2: fc2 (8).
__global__ void __launch_bounds__(NT_C) k_C(
    const void* state, const int* agent_p,
    const void* conv_w, const void* conv_b,
    const void* fc1_w, const void* fc1_b, const void* ln1_w, const void* ln1_b,
    const void* fc2_w, const void* fc2_b, const void* ln2_w, const void* ln2_b,
    const void* mu_w, const void* mu_b,
    int* wsi, void* out)
{
    __shared__ float s_wl[8192];     // 32KB weight slice
    __shared__ float s_in[D_HID];
    __shared__ float s_part[NT_C];
    __shared__ float s_xs[D_IN];
    __shared__ float s_red[8];
    __shared__ int   s_src[MAXG];
    __shared__ float s_w[MAXG];
    __shared__ int   s_b16;

    int tid = threadIdx.x, bid = blockIdx.x;
    bool b16 = detect_b16(state, tid, &s_b16) != 0;
    float* wsf = (float*)wsi;
    int* bar = wsi + OFF_BAR;

    // ---- preload weight slice into LDS (before any waiting) ----
    if (bid < 8) {
        int o0 = bid * 32;
        for (int i = tid; i < D_IN * 32; i += NT_C)
            s_wl[i] = ldf(conv_w, (long long)(i >> 5) * D_HID + o0 + (i & 31), b16);
    } else if (bid < 16) {
        int o0 = (bid - 8) * 32;
        for (int i = tid; i < D_HID * 32; i += NT_C)
            s_wl[i] = ldf(fc1_w, (long long)(i >> 5) * D_HID + o0 + (i & 31), b16);
    } else if (bid < 24) {
        int o0 = (bid - 16) * 32;
        for (int i = tid; i < D_HID * 32; i += NT_C)
            s_wl[i] = ldf(fc2_w, (long long)(i >> 5) * D_HID + o0 + (i & 31), b16);
    } else {
        for (int i = tid; i < D_HID * 8; i += NT_C)
            s_wl[i] = ldf(mu_w, i, b16);
    }

    // ---- conv blocks 0..7: gather + LDS matvec slice -> H0; arrive slot0 ----
    if (bid < 8) {
        int m = wsi[OFF_M];
        m = m < MAXG ? m : MAXG;
        int agent = agent_p[0];
        float dinv_a = rsqrtf((float)(ALD(&wsi[OFF_DEG]) + 1));
        for (int i = tid; i < m; i += NT_C) {
            s_src[i] = wsi[OFF_CM + i];
            int u = wsi[OFF_MAP + 1 + i];
            s_w[i] = dinv_a * rsqrtf((float)(ALD(&wsi[OFF_DEG + u]) + 1));
        }
        __syncthreads();
        int d = tid & 127, jg = tid >> 7;   // 4 j-groups x 128 dims
        float acc = (jg == 0) ? dinv_a * dinv_a * ldf(state, (long long)agent * D_IN + d, b16) : 0.0f;
        for (int j = jg; j < m; j += 4)
            acc += s_w[j] * ldf(state, (long long)s_src[j] * D_IN + d, b16);
        s_part[tid] = acc;
        __syncthreads();
        if (tid < D_IN)
            s_xs[tid] = s_part[tid] + s_part[tid + 128] + s_part[tid + 256] + s_part[tid + 384];
        __syncthreads();
        int c = tid & 31, ks = tid >> 5;   // 16 k-slices of 8
        float a = 0.0f;
        #pragma unroll 8
        for (int k = ks * 8; k < ks * 8 + 8; k++)
            a += s_xs[k] * s_wl[k * 32 + c];
        s_part[tid] = a;
        __syncthreads();
        if (tid < 32) {
            int oo = bid * 32 + tid;
            float h = ldf(conv_b, oo, b16);
            #pragma unroll
            for (int s2 = 0; s2 < 16; s2++) h += s_part[s2 * 32 + tid];
            AST(&wsf[OFF_H0 + oo], fmaxf(h, 0.0f));
        }
        bar_arrive(&bar[0]);
        return;
    }

    // ---- fc1 blocks 8..15: wait conv, LDS matvec -> h1raw; arrive slot1 ----
    if (bid < 16) {
        bar_wait(&bar[0], 8);
        if (tid < D_HID) s_in[tid] = ALD(&wsf[OFF_H0 + tid]);
        __syncthreads();
        int c = tid & 31, ks = tid >> 5;   // 16 slices x 16 k
        float a = 0.0f;
        #pragma unroll 8
        for (int k = ks * 16; k < ks * 16 + 16; k++)
            a += s_in[k] * s_wl[k * 32 + c];
        s_part[tid] = a;
        __syncthreads();
        if (tid < 32) {
            int oo = (bid - 8) * 32 + tid;
            float h = ldf(fc1_b, oo, b16);
            #pragma unroll
            for (int s2 = 0; s2 < 16; s2++) h += s_part[s2 * 32 + tid];
            AST(&wsf[OFF_H1 + oo], h);
        }
        bar_arrive(&bar[1]);
        return;
    }

    // ---- fc2 blocks 16..23: wait fc1, LN1+relu inline, matvec -> h2raw ----
    if (bid < 24) {
        bar_wait(&bar[1], 8);
        float v = (tid < D_HID) ? ALD(&wsf[OFF_H1 + tid]) : 0.0f;
        float y = ln256(v, ln1_w, ln1_b, s_red, tid, b16);
        if (tid < D_HID) s_in[tid] = y;
        __syncthreads();
        int c = tid & 31, ks = tid >> 5;
        float a = 0.0f;
        #pragma unroll 8
        for (int k = ks * 16; k < ks * 16 + 16; k++)
            a += s_in[k] * s_wl[k * 32 + c];
        s_part[tid] = a;
        __syncthreads();
        if (tid < 32) {
            int oo = (bid - 16) * 32 + tid;
            float h = ldf(fc2_b, oo, b16);
            #pragma unroll
            for (int s2 = 0; s2 < 16; s2++) h += s_part[s2 * 32 + tid];
            AST(&wsf[OFF_H2 + oo], h);
        }
        bar_arrive(&bar[2]);
        return;
    }

    // ---- mu block 24: wait fc2, LN2+relu, 256x8 LDS matvec, sigmoid ----
    {
        bar_wait(&bar[2], 8);
        float v = (tid < D_HID) ? ALD(&wsf[OFF_H2 + tid]) : 0.0f;
        float y = ln256(v, ln2_w, ln2_b, s_red, tid, b16);
        if (tid < D_HID) s_in[tid] = y;
        __syncthreads();
        int o = tid & 7, ks = tid >> 3;   // 64 slices x 4 k
        float a = 0.0f;
        #pragma unroll
        for (int k = ks * 4; k < ks * 4 + 4; k++)
            a += s_in[k] * s_wl[k * 8 + o];
        s_part[tid] = a;
        __syncthreads();
        if (tid < 8) {
            float acc = ldf(mu_b, tid, b16);
            #pragma unroll
            for (int s2 = 0; s2 < 64; s2++) acc += s_part[s2 * 8 + tid];
            float r = 1.0f / (1.0f + expf(-acc));
            if (b16) ((__hip_bfloat16*)out)[tid] = __float2bfloat16(r);
            else     ((float*)out)[tid] = r;
        }
    }
}

extern "C" void kernel_launch(void* const* d_in, const int* in_sizes, int n_in,
                              void* d_out, int out_size, void* d_ws, size_t ws_size,
                              hipStream_t stream) {
    const void* state = d_in[0];
    const void* edges = d_in[1];
    const int* agent = (const int*)d_in[2];
    int* wsi = (int*)d_ws;
    long long n_edges = in_sizes[1] / 2;

    k_A<<<NB_A, NT_A, 0, stream>>>(edges, state, agent,
                                   d_in[3], d_in[5], d_in[9], d_in[13],
                                   wsi, n_edges);
    k_B<<<NB_B, NT_B, 0, stream>>>(edges, agent, wsi, n_edges);
    k_C<<<25, NT_C, 0, stream>>>(state, agent,
                                 d_in[3], d_in[4],
                                 d_in[5], d_in[6], d_in[7], d_in[8],
                                 d_in[9], d_in[10], d_in[11], d_in[12],
                                 d_in[13], d_in[14],
                                 wsi, d_out);
}

// Round 12
// 34.045 us; speedup vs baseline: 1.1821x; 1.0564x over previous
//
#include <hip/hip_runtime.h>
#include <hip/hip_bf16.h>

#define D_IN  128
#define D_HID 256
#define NB_A  256
#define NT_A  512
#define NB_B  256
#define NT_B  512
#define NT_C  512
#define MAXG  512
#define HASHN 2048
#define PBM_STRIDE 72

// ws int layout:
//  [0..7]     barrier slots for kernel C (zeroed by A block 0)
//  [16]       m (compact match count, written by B block 0)
//  [32..544]  per-unique-node degree sums (u=0 agent), zeroed by A, atomicAdd by B
//  [1024..]   per-A-block match regions (NB_A x PBM_STRIDE)
//  [20480..]  compact match src list (MAXG)
//  [21504..]  map j -> unique index u (MAXG+1 entries, j=0 is agent)
//  floats:    [24576]=h0[256], [25088]=h1raw[256], [25600]=h2raw[256]
#define OFF_BAR  0
#define OFF_M    16
#define OFF_DEG  32
#define OFF_PBM  1024
#define OFF_CM   20480
#define OFF_MAP  21504
#define OFF_H0   24576
#define OFF_H1   25088
#define OFF_H2   25600

#define ALD(p)   __hip_atomic_load((p),      __ATOMIC_RELAXED, __HIP_MEMORY_SCOPE_AGENT)
#define AST(p,v) __hip_atomic_store((p),(v), __ATOMIC_RELAXED, __HIP_MEMORY_SCOPE_AGENT)

__device__ __forceinline__ float ldf(const void* p, long long i, bool b16) {
    if (b16) {
        unsigned short u = ((const unsigned short*)p)[i];
        return __uint_as_float(((unsigned int)u) << 16);
    }
    return ((const float*)p)[i];
}

// paired load of elements i, i+1 (i even)
__device__ __forceinline__ void ld2(const void* p, long long i, bool b16, float& a, float& b) {
    if (b16) {
        unsigned int u = ((const unsigned int*)p)[i >> 1];
        a = __uint_as_float(u << 16);
        b = __uint_as_float(u & 0xffff0000u);
    } else {
        float2 v = ((const float2*)p)[i >> 1];
        a = v.x; b = v.y;
    }
}

__device__ __forceinline__ unsigned hash_n(int key) {
    return (((unsigned)key * 2654435761u) >> 21) & (HASHN - 1);
}

__device__ __forceinline__ int detect_i64(const void* edges, int tid, int* s) {
    if (tid < 64) {
        const unsigned* w = (const unsigned*)edges;
        unsigned long long b = __ballot(w[2 * tid + 1] == 0u);
        if (tid == 0) *s = (b == ~0ULL) ? 1 : 0;
    }
    __syncthreads();
    return *s;
}

__device__ __forceinline__ int detect_b16(const void* state, int tid, int* s) {
    if (tid < 64) {
        const unsigned short* p = (const unsigned short*)state;
        unsigned short v = p[tid];
        int e = (v >> 7) & 0xff;
        unsigned long long b = __ballot(v == 0 || (e >= 90 && e <= 140));
        if (tid == 0) *s = (b == ~0ULL) ? 1 : 0;
    }
    __syncthreads();
    return *s;
}

// producer-side arrival: one fenced RELEASE add, no spin.
__device__ __forceinline__ void bar_arrive(int* slot) {
    __syncthreads();
    if (threadIdx.x == 0) {
        __threadfence();
        __hip_atomic_fetch_add(slot, 1, __ATOMIC_RELEASE, __HIP_MEMORY_SCOPE_AGENT);
    }
}

// consumer-side wait: RELAXED spin (R8 lesson: no acquire polling), fence on exit.
__device__ __forceinline__ void bar_wait(int* slot, int cnt) {
    if (threadIdx.x == 0) {
        while (__hip_atomic_load(slot, __ATOMIC_RELAXED, __HIP_MEMORY_SCOPE_AGENT) < cnt)
            __builtin_amdgcn_s_sleep(2);
        __threadfence();
    }
    __syncthreads();
}

// A: zero control state (block 0) + 8-wide match scan + weight L3-prefetch.
__global__ void __launch_bounds__(NT_A) k_A(const void* edges, const void* state,
                                            const int* agent_p,
                                            const void* w0, const void* w1,
                                            const void* w2, const void* w3,
                                            int* wsi, long long n_edges) {
    __shared__ int s_pref[NT_A];
    __shared__ int s_list[64];
    __shared__ int s_i64, s_b16;
    int tid = threadIdx.x, bid = blockIdx.x;
    int i64 = detect_i64(edges, tid, &s_i64);
    int b16 = detect_b16(state, tid, &s_b16);

    if (bid == 0) {
        if (tid < 8) AST(&wsi[OFF_BAR + tid], 0);
        for (int i = tid; i <= MAXG; i += NT_A) AST(&wsi[OFF_DEG + i], 0);
    }

    // prefetch weights into L3: one dword per 64B line, spread over the grid
    {
        int esz = b16 ? 2 : 4;
        long long gt = (long long)bid * NT_A + tid;
        const void* arr[4] = { w0, w1, w2, w3 };
        const int elems[4] = { D_IN * D_HID, D_HID * D_HID, D_HID * D_HID, D_HID * 8 };
        long long base = 0;
        #pragma unroll
        for (int a = 0; a < 4; a++) {
            long long lines = ((long long)elems[a] * esz) >> 6;
            long long idx = gt - base;
            if (idx >= 0 && idx < lines) {
                unsigned v = *(const unsigned*)((const char*)arr[a] + (idx << 6));
                asm volatile("" :: "v"(v));
            }
            base += lines;
        }
    }

    int agent = agent_p[0];
    long long base8 = ((long long)bid * NT_A + tid) * 8;
    const long long stride8 = (long long)NB_A * NT_A * 8;
    long long nv = n_edges & ~7LL;
    int c = 0;
    if (i64) {
        const long long* dst = (const long long*)edges + n_edges;
        for (long long e = base8; e < nv; e += stride8) {
            long2 a0 = *(const long2*)(dst + e);
            long2 a1 = *(const long2*)(dst + e + 2);
            long2 a2 = *(const long2*)(dst + e + 4);
            long2 a3 = *(const long2*)(dst + e + 6);
            c += ((int)a0.x == agent) + ((int)a0.y == agent)
               + ((int)a1.x == agent) + ((int)a1.y == agent)
               + ((int)a2.x == agent) + ((int)a2.y == agent)
               + ((int)a3.x == agent) + ((int)a3.y == agent);
        }
        if (bid == 0 && tid == 0)
            for (long long e = nv; e < n_edges; e++) c += ((int)dst[e] == agent);
    } else {
        const int* dst = (const int*)edges + n_edges;
        for (long long e = base8; e < nv; e += stride8) {
            int4 a = *(const int4*)(dst + e);
            int4 b = *(const int4*)(dst + e + 4);
            c += (a.x == agent) + (a.y == agent) + (a.z == agent) + (a.w == agent)
               + (b.x == agent) + (b.y == agent) + (b.z == agent) + (b.w == agent);
        }
        if (bid == 0 && tid == 0)
            for (long long e = nv; e < n_edges; e++) c += (dst[e] == agent);
    }
    s_pref[tid] = c;
    __syncthreads();
    #pragma unroll
    for (int off = 1; off < NT_A; off <<= 1) {
        int v = (tid >= off) ? s_pref[tid - off] : 0;
        __syncthreads();
        s_pref[tid] += v;
        __syncthreads();
    }
    int excl = s_pref[tid] - c;
    int total = s_pref[NT_A - 1];
    if (c > 0 && excl < 64) {
        int k = excl;
        if (i64) {
            const long long* src = (const long long*)edges;
            const long long* dst = src + n_edges;
            for (long long e = base8; e < nv; e += stride8) {
                #pragma unroll
                for (int q = 0; q < 8; q++) {
                    if ((int)dst[e + q] == agent) { if (k < 64) s_list[k] = (int)src[e + q]; k++; }
                }
            }
            if (bid == 0 && tid == 0)
                for (long long e = nv; e < n_edges; e++)
                    if ((int)dst[e] == agent) { if (k < 64) s_list[k] = (int)src[e]; k++; }
        } else {
            const int* src = (const int*)edges;
            const int* dst = src + n_edges;
            for (long long e = base8; e < nv; e += stride8) {
                #pragma unroll
                for (int q = 0; q < 8; q++) {
                    if (dst[e + q] == agent) { if (k < 64) s_list[k] = src[e + q]; k++; }
                }
            }
            if (bid == 0 && tid == 0)
                for (long long e = nv; e < n_edges; e++)
                    if (dst[e] == agent) { if (k < 64) s_list[k] = src[e]; k++; }
        }
    }
    __syncthreads();
    int* reg = wsi + OFF_PBM + bid * PBM_STRIDE;
    int tw = total < 64 ? total : 64;
    if (tid == 0) reg[0] = tw;
    if (tid < tw) reg[1 + tid] = s_list[tid];
}

// B: rebuild compact match list, LDS hash, 8-wide degree count, export counts +
// compact list + j->u map. Blocks 0..7 also L3-prefetch the needed state rows.
__global__ void __launch_bounds__(NT_B) k_B(const void* edges, const void* state,
                                            const int* agent_p,
                                            int* wsi, long long n_edges) {
    __shared__ int s_pref[NT_B];
    __shared__ int s_nodes[MAXG + 1];
    __shared__ int s_hkey[HASHN];
    __shared__ int s_hval[HASHN];
    __shared__ int s_cnt[MAXG + 1];
    __shared__ int s_i64, s_b16, s_nu;
    int tid = threadIdx.x, bid = blockIdx.x;
    int i64 = detect_i64(edges, tid, &s_i64);
    bool b16 = detect_b16(state, tid, &s_b16) != 0;

    int bc = 0;
    if (tid < NB_A) {
        bc = wsi[OFF_PBM + tid * PBM_STRIDE];
        bc = bc < 64 ? (bc < 0 ? 0 : bc) : 64;
    }
    s_pref[tid] = bc;
    __syncthreads();
    #pragma unroll
    for (int off = 1; off < NT_B; off <<= 1) {
        int v = (tid >= off) ? s_pref[tid - off] : 0;
        __syncthreads();
        s_pref[tid] += v;
        __syncthreads();
    }
    int excl = s_pref[tid] - bc;
    int mc = s_pref[NT_B - 1];
    int m = mc < MAXG ? mc : MAXG;
    if (tid < NB_A) {
        for (int i = 0; i < bc; i++) {
            int g = excl + i;
            if (g < MAXG) s_nodes[1 + g] = wsi[OFF_PBM + tid * PBM_STRIDE + 1 + i];
        }
    }
    if (tid == 0) s_nodes[0] = agent_p[0];
    for (int i = tid; i < HASHN; i += NT_B) s_hkey[i] = -1;
    for (int i = tid; i <= m; i += NT_B) s_cnt[i] = 0;
    __syncthreads();

    if (tid == 0) {
        int nu = 0;
        for (int j = 0; j <= m; j++) {
            int key = s_nodes[j];
            unsigned h = hash_n(key);
            while (true) {
                if (s_hkey[h] == -1) { s_hkey[h] = key; s_hval[h] = nu++; break; }
                if (s_hkey[h] == key) break;
                h = (h + 1) & (HASHN - 1);
            }
        }
        s_nu = nu;
    }
    __syncthreads();

    // blocks 0..7: L3-prefetch the m+1 needed state rows (overlaps degree count)
    if (bid < 8) {
        int esz = b16 ? 2 : 4;
        int chunks = (D_IN * esz) >> 6;   // 64B lines per row
        for (int i = tid; i < (m + 1) * chunks; i += NT_B) {
            int j = i / chunks, ch = i - j * chunks;
            long long row = s_nodes[j];
            unsigned v = *(const unsigned*)((const char*)state + row * D_IN * esz + ch * 64);
            asm volatile("" :: "v"(v));
        }
    }

    auto probe = [&](int d) {
        unsigned h = hash_n(d);
        while (true) {
            int k = s_hkey[h];
            if (k == -1) break;
            if (k == d) { atomicAdd(&s_cnt[s_hval[h]], 1); break; }
            h = (h + 1) & (HASHN - 1);
        }
    };

    long long base8 = ((long long)bid * NT_B + tid) * 8;
    const long long stride8 = (long long)NB_B * NT_B * 8;
    long long nv = n_edges & ~7LL;
    if (i64) {
        const long long* dst = (const long long*)edges + n_edges;
        for (long long e = base8; e < nv; e += stride8) {
            long2 a0 = *(const long2*)(dst + e);
            long2 a1 = *(const long2*)(dst + e + 2);
            long2 a2 = *(const long2*)(dst + e + 4);
            long2 a3 = *(const long2*)(dst + e + 6);
            probe((int)a0.x); probe((int)a0.y); probe((int)a1.x); probe((int)a1.y);
            probe((int)a2.x); probe((int)a2.y); probe((int)a3.x); probe((int)a3.y);
        }
        if (bid == 0 && tid == 0)
            for (long long e = nv; e < n_edges; e++) probe((int)dst[e]);
    } else {
        const int* dst = (const int*)edges + n_edges;
        for (long long e = base8; e < nv; e += stride8) {
            int4 a = *(const int4*)(dst + e);
            int4 b = *(const int4*)(dst + e + 4);
            probe(a.x); probe(a.y); probe(a.z); probe(a.w);
            probe(b.x); probe(b.y); probe(b.z); probe(b.w);
        }
        if (bid == 0 && tid == 0)
            for (long long e = nv; e < n_edges; e++) probe(dst[e]);
    }
    __syncthreads();
    int nu = s_nu;
    for (int i = tid; i < nu; i += NT_B)
        if (s_cnt[i]) atomicAdd(&wsi[OFF_DEG + i], s_cnt[i]);
    if (bid == 0) {
        if (tid == 0) wsi[OFF_M] = m;
        for (int i = tid; i < m; i += NT_B) wsi[OFF_CM + i] = s_nodes[1 + i];
        for (int j = tid; j <= m; j += NT_B) {
            int key = s_nodes[j];
            unsigned h = hash_n(key);
            while (s_hkey[h] != key) h = (h + 1) & (HASHN - 1);
            wsi[OFF_MAP + j] = s_hval[h];
        }
    }
}

__device__ __forceinline__ float ln256(float v, const void* lnw, const void* lnb,
                                       float* s_red, int tid, bool b16) {
    if (tid < 256) {
        float x = v;
        #pragma unroll
        for (int o = 32; o > 0; o >>= 1) x += __shfl_down(x, o);
        if ((tid & 63) == 0) s_red[tid >> 6] = x;
    }
    __syncthreads();
    float mu = (s_red[0] + s_red[1] + s_red[2] + s_red[3]) * (1.0f / 256.0f);
    if (tid < 256) {
        float dd = v - mu;
        float x = dd * dd;
        #pragma unroll
        for (int o = 32; o > 0; o >>= 1) x += __shfl_down(x, o);
        if ((tid & 63) == 0) s_red[4 + (tid >> 6)] = x;
    }
    __syncthreads();
    float var = (s_red[4] + s_red[5] + s_red[6] + s_red[7]) * (1.0f / 256.0f);
    float y = 0.0f;
    if (tid < 256)
        y = fmaxf((v - mu) * rsqrtf(var + 1e-5f) * ldf(lnw, tid, b16) + ldf(lnb, tid, b16), 0.0f);
    __syncthreads();
    return y;
}

// C: 25-block MLP pipeline, LDS-preloaded weight slices, producer-only barriers.
__global__ void __launch_bounds__(NT_C) k_C(
    const void* state, const int* agent_p,
    const void* conv_w, const void* conv_b,
    const void* fc1_w, const void* fc1_b, const void* ln1_w, const void* ln1_b,
    const void* fc2_w, const void* fc2_b, const void* ln2_w, const void* ln2_b,
    const void* mu_w, const void* mu_b,
    int* wsi, void* out)
{
    __shared__ float s_wl[8192];     // 32KB weight slice
    __shared__ float s_g[1024];      // gather scratch (8 j-groups x 128 dims)
    __shared__ float s_in[D_HID];
    __shared__ float s_part[NT_C];
    __shared__ float s_xs[D_IN];
    __shared__ float s_red[8];
    __shared__ int   s_src[MAXG];
    __shared__ float s_w[MAXG];
    __shared__ int   s_b16;

    int tid = threadIdx.x, bid = blockIdx.x;
    bool b16 = detect_b16(state, tid, &s_b16) != 0;
    float* wsf = (float*)wsi;
    int* bar = wsi + OFF_BAR;

    // ---- preload weight slice into LDS (before any waiting) ----
    if (bid < 8) {
        int o0 = bid * 32;
        for (int i = tid; i < D_IN * 32; i += NT_C)
            s_wl[i] = ldf(conv_w, (long long)(i >> 5) * D_HID + o0 + (i & 31), b16);
    } else if (bid < 16) {
        int o0 = (bid - 8) * 32;
        for (int i = tid; i < D_HID * 32; i += NT_C)
            s_wl[i] = ldf(fc1_w, (long long)(i >> 5) * D_HID + o0 + (i & 31), b16);
    } else if (bid < 24) {
        int o0 = (bid - 16) * 32;
        for (int i = tid; i < D_HID * 32; i += NT_C)
            s_wl[i] = ldf(fc2_w, (long long)(i >> 5) * D_HID + o0 + (i & 31), b16);
    } else {
        for (int i = tid; i < D_HID * 8; i += NT_C)
            s_wl[i] = ldf(mu_w, i, b16);
    }

    // ---- conv blocks 0..7: gather (8-way split) + LDS matvec -> H0 ----
    if (bid < 8) {
        int m = wsi[OFF_M];
        m = m < MAXG ? m : MAXG;
        int agent = agent_p[0];
        float dinv_a = rsqrtf((float)(ALD(&wsi[OFF_DEG]) + 1));
        for (int i = tid; i < m; i += NT_C) {
            s_src[i] = wsi[OFF_CM + i];
            int u = wsi[OFF_MAP + 1 + i];
            s_w[i] = dinv_a * rsqrtf((float)(ALD(&wsi[OFF_DEG + u]) + 1));
        }
        __syncthreads();
        // 8 j-groups x 64 d-pairs (state rows L3-warm from k_B prefetch)
        int jg = tid >> 6;
        int d2 = (tid & 63) * 2;
        float a0 = 0.0f, a1 = 0.0f;
        if (jg == 0) {
            float sa, sb;
            ld2(state, (long long)agent * D_IN + d2, b16, sa, sb);
            a0 = dinv_a * dinv_a * sa;
            a1 = dinv_a * dinv_a * sb;
        }
        for (int j = jg; j < m; j += 8) {
            float sa, sb;
            ld2(state, (long long)s_src[j] * D_IN + d2, b16, sa, sb);
            float w = s_w[j];
            a0 += w * sa;
            a1 += w * sb;
        }
        s_g[jg * 128 + d2]     = a0;
        s_g[jg * 128 + d2 + 1] = a1;
        __syncthreads();
        if (tid < D_IN) {
            float acc = 0.0f;
            #pragma unroll
            for (int g = 0; g < 8; g++) acc += s_g[g * 128 + tid];
            s_xs[tid] = acc;
        }
        __syncthreads();
        int c = tid & 31, ks = tid >> 5;   // 16 k-slices of 8
        float a = 0.0f;
        #pragma unroll 8
        for (int k = ks * 8; k < ks * 8 + 8; k++)
            a += s_xs[k] * s_wl[k * 32 + c];
        s_part[tid] = a;
        __syncthreads();
        if (tid < 32) {
            int oo = bid * 32 + tid;
            float h = ldf(conv_b, oo, b16);
            #pragma unroll
            for (int s2 = 0; s2 < 16; s2++) h += s_part[s2 * 32 + tid];
            AST(&wsf[OFF_H0 + oo], fmaxf(h, 0.0f));
        }
        bar_arrive(&bar[0]);
        return;
    }

    // ---- fc1 blocks 8..15: wait conv, LDS matvec -> h1raw ----
    if (bid < 16) {
        bar_wait(&bar[0], 8);
        if (tid < D_HID) s_in[tid] = ALD(&wsf[OFF_H0 + tid]);
        __syncthreads();
        int c = tid & 31, ks = tid >> 5;   // 16 slices x 16 k
        float a = 0.0f;
        #pragma unroll 8
        for (int k = ks * 16; k < ks * 16 + 16; k++)
            a += s_in[k] * s_wl[k * 32 + c];
        s_part[tid] = a;
        __syncthreads();
        if (tid < 32) {
            int oo = (bid - 8) * 32 + tid;
            float h = ldf(fc1_b, oo, b16);
            #pragma unroll
            for (int s2 = 0; s2 < 16; s2++) h += s_part[s2 * 32 + tid];
            AST(&wsf[OFF_H1 + oo], h);
        }
        bar_arrive(&bar[1]);
        return;
    }

    // ---- fc2 blocks 16..23: wait fc1, LN1+relu inline, matvec -> h2raw ----
    if (bid < 24) {
        bar_wait(&bar[1], 8);
        float v = (tid < D_HID) ? ALD(&wsf[OFF_H1 + tid]) : 0.0f;
        float y = ln256(v, ln1_w, ln1_b, s_red, tid, b16);
        if (tid < D_HID) s_in[tid] = y;
        __syncthreads();
        int c = tid & 31, ks = tid >> 5;
        float a = 0.0f;
        #pragma unroll 8
        for (int k = ks * 16; k < ks * 16 + 16; k++)
            a += s_in[k] * s_wl[k * 32 + c];
        s_part[tid] = a;
        __syncthreads();
        if (tid < 32) {
            int oo = (bid - 16) * 32 + tid;
            float h = ldf(fc2_b, oo, b16);
            #pragma unroll
            for (int s2 = 0; s2 < 16; s2++) h += s_part[s2 * 32 + tid];
            AST(&wsf[OFF_H2 + oo], h);
        }
        bar_arrive(&bar[2]);
        return;
    }

    // ---- mu block 24: wait fc2, LN2+relu, 256x8 LDS matvec, sigmoid ----
    {
        bar_wait(&bar[2], 8);
        float v = (tid < D_HID) ? ALD(&wsf[OFF_H2 + tid]) : 0.0f;
        float y = ln256(v, ln2_w, ln2_b, s_red, tid, b16);
        if (tid < D_HID) s_in[tid] = y;
        __syncthreads();
        int o = tid & 7, ks = tid >> 3;   // 64 slices x 4 k
        float a = 0.0f;
        #pragma unroll
        for (int k = ks * 4; k < ks * 4 + 4; k++)
            a += s_in[k] * s_wl[k * 8 + o];
        s_part[tid] = a;
        __syncthreads();
        if (tid < 8) {
            float acc = ldf(mu_b, tid, b16);
            #pragma unroll
            for (int s2 = 0; s2 < 64; s2++) acc += s_part[s2 * 8 + tid];
            float r = 1.0f / (1.0f + expf(-acc));
            if (b16) ((__hip_bfloat16*)out)[tid] = __float2bfloat16(r);
            else     ((float*)out)[tid] = r;
        }
    }
}

extern "C" void kernel_launch(void* const* d_in, const int* in_sizes, int n_in,
                              void* d_out, int out_size, void* d_ws, size_t ws_size,
                              hipStream_t stream) {
    const void* state = d_in[0];
    const void* edges = d_in[1];
    const int* agent = (const int*)d_in[2];
    int* wsi = (int*)d_ws;
    long long n_edges = in_sizes[1] / 2;

    k_A<<<NB_A, NT_A, 0, stream>>>(edges, state, agent,
                                   d_in[3], d_in[5], d_in[9], d_in[13],
                                   wsi, n_edges);
    k_B<<<NB_B, NT_B, 0, stream>>>(edges, state, agent, wsi, n_edges);
    k_C<<<25, NT_C, 0, stream>>>(state, agent,
                                 d_in[3], d_in[4],
                                 d_in[5], d_in[6], d_in[7], d_in[8],
                                 d_in[9], d_in[10], d_in[11], d_in[12],
                                 d_in[13], d_in[14],
                                 wsi, d_out);
}

// Round 13
// 31.250 us; speedup vs baseline: 1.2878x; 1.0894x over previous
//
#include <hip/hip_runtime.h>
#include <hip/hip_bf16.h>

#define D_IN  128
#define D_HID 256
#define NB_A  256
#define NT_A  512
#define NB_B  256
#define NT_B  512
#define NT_C  512
#define MAXG  512
#define HASHN 2048
#define PBM_STRIDE 72

// ws int layout:
//  [0..7]        barrier slots for kernel C (zeroed by A block 0)
//  [16]          m (compact match count, written by B block 0)
//  [1024..19456] per-A-block match regions (NB_A x PBM_STRIDE)
//  [20480..]     compact match src list (MAXG)
//  [21504..]     map j -> representative index r (MAXG+1 entries, j=0 agent)
//  [24576..]     degree sums, PADDED: counter r lives at OFF_DEG + r*16 (one line each)
//  floats:       [33024]=h0[256], [33536]=h1raw[256], [34048]=h2raw[256]
#define OFF_BAR  0
#define OFF_M    16
#define OFF_PBM  1024
#define OFF_CM   20480
#define OFF_MAP  21504
#define OFF_DEG  24576
#define OFF_H0   33024
#define OFF_H1   33536
#define OFF_H2   34048

#define ALD(p)   __hip_atomic_load((p),      __ATOMIC_RELAXED, __HIP_MEMORY_SCOPE_AGENT)
#define AST(p,v) __hip_atomic_store((p),(v), __ATOMIC_RELAXED, __HIP_MEMORY_SCOPE_AGENT)

__device__ __forceinline__ float ldf(const void* p, long long i, bool b16) {
    if (b16) {
        unsigned short u = ((const unsigned short*)p)[i];
        return __uint_as_float(((unsigned int)u) << 16);
    }
    return ((const float*)p)[i];
}

// paired load of elements i, i+1 (i even)
__device__ __forceinline__ void ld2(const void* p, long long i, bool b16, float& a, float& b) {
    if (b16) {
        unsigned int u = ((const unsigned int*)p)[i >> 1];
        a = __uint_as_float(u << 16);
        b = __uint_as_float(u & 0xffff0000u);
    } else {
        float2 v = ((const float2*)p)[i >> 1];
        a = v.x; b = v.y;
    }
}

__device__ __forceinline__ unsigned hash_n(int key) {
    return (((unsigned)key * 2654435761u) >> 21) & (HASHN - 1);
}

__device__ __forceinline__ int detect_i64(const void* edges, int tid, int* s) {
    if (tid < 64) {
        const unsigned* w = (const unsigned*)edges;
        unsigned long long b = __ballot(w[2 * tid + 1] == 0u);
        if (tid == 0) *s = (b == ~0ULL) ? 1 : 0;
    }
    __syncthreads();
    return *s;
}

__device__ __forceinline__ int detect_b16(const void* state, int tid, int* s) {
    if (tid < 64) {
        const unsigned short* p = (const unsigned short*)state;
        unsigned short v = p[tid];
        int e = (v >> 7) & 0xff;
        unsigned long long b = __ballot(v == 0 || (e >= 90 && e <= 140));
        if (tid == 0) *s = (b == ~0ULL) ? 1 : 0;
    }
    __syncthreads();
    return *s;
}

// producer-side arrival: one fenced RELEASE add, no spin.
__device__ __forceinline__ void bar_arrive(int* slot) {
    __syncthreads();
    if (threadIdx.x == 0) {
        __threadfence();
        __hip_atomic_fetch_add(slot, 1, __ATOMIC_RELEASE, __HIP_MEMORY_SCOPE_AGENT);
    }
}

// consumer-side wait: RELAXED spin (R8 lesson: no acquire polling), fence on exit.
__device__ __forceinline__ void bar_wait(int* slot, int cnt) {
    if (threadIdx.x == 0) {
        while (__hip_atomic_load(slot, __ATOMIC_RELAXED, __HIP_MEMORY_SCOPE_AGENT) < cnt)
            __builtin_amdgcn_s_sleep(2);
        __threadfence();
    }
    __syncthreads();
}

// A: zero control state (block 0) + 8-wide match scan + weight L3-prefetch.
__global__ void __launch_bounds__(NT_A) k_A(const void* edges, const void* state,
                                            const int* agent_p,
                                            const void* w0, const void* w1,
                                            const void* w2, const void* w3,
                                            int* wsi, long long n_edges) {
    __shared__ int s_pref[NT_A];
    __shared__ int s_list[64];
    __shared__ int s_i64, s_b16;
    int tid = threadIdx.x, bid = blockIdx.x;
    int i64 = detect_i64(edges, tid, &s_i64);
    int b16 = detect_b16(state, tid, &s_b16);

    if (bid == 0) {
        if (tid < 8) AST(&wsi[OFF_BAR + tid], 0);
        for (int i = tid; i < (MAXG + 1) * 16; i += NT_A) AST(&wsi[OFF_DEG + i], 0);
    }

    // prefetch weights into L3: one dword per 64B line, spread over the grid
    {
        int esz = b16 ? 2 : 4;
        long long gt = (long long)bid * NT_A + tid;
        const void* arr[4] = { w0, w1, w2, w3 };
        const int elems[4] = { D_IN * D_HID, D_HID * D_HID, D_HID * D_HID, D_HID * 8 };
        long long base = 0;
        #pragma unroll
        for (int a = 0; a < 4; a++) {
            long long lines = ((long long)elems[a] * esz) >> 6;
            long long idx = gt - base;
            if (idx >= 0 && idx < lines) {
                unsigned v = *(const unsigned*)((const char*)arr[a] + (idx << 6));
                asm volatile("" :: "v"(v));
            }
            base += lines;
        }
    }

    int agent = agent_p[0];
    long long base8 = ((long long)bid * NT_A + tid) * 8;
    const long long stride8 = (long long)NB_A * NT_A * 8;
    long long nv = n_edges & ~7LL;
    int c = 0;
    if (i64) {
        const long long* dst = (const long long*)edges + n_edges;
        for (long long e = base8; e < nv; e += stride8) {
            long2 a0 = *(const long2*)(dst + e);
            long2 a1 = *(const long2*)(dst + e + 2);
            long2 a2 = *(const long2*)(dst + e + 4);
            long2 a3 = *(const long2*)(dst + e + 6);
            c += ((int)a0.x == agent) + ((int)a0.y == agent)
               + ((int)a1.x == agent) + ((int)a1.y == agent)
               + ((int)a2.x == agent) + ((int)a2.y == agent)
               + ((int)a3.x == agent) + ((int)a3.y == agent);
        }
        if (bid == 0 && tid == 0)
            for (long long e = nv; e < n_edges; e++) c += ((int)dst[e] == agent);
    } else {
        const int* dst = (const int*)edges + n_edges;
        for (long long e = base8; e < nv; e += stride8) {
            int4 a = *(const int4*)(dst + e);
            int4 b = *(const int4*)(dst + e + 4);
            c += (a.x == agent) + (a.y == agent) + (a.z == agent) + (a.w == agent)
               + (b.x == agent) + (b.y == agent) + (b.z == agent) + (b.w == agent);
        }
        if (bid == 0 && tid == 0)
            for (long long e = nv; e < n_edges; e++) c += (dst[e] == agent);
    }
    s_pref[tid] = c;
    __syncthreads();
    #pragma unroll
    for (int off = 1; off < NT_A; off <<= 1) {
        int v = (tid >= off) ? s_pref[tid - off] : 0;
        __syncthreads();
        s_pref[tid] += v;
        __syncthreads();
    }
    int excl = s_pref[tid] - c;
    int total = s_pref[NT_A - 1];
    if (c > 0 && excl < 64) {
        int k = excl;
        if (i64) {
            const long long* src = (const long long*)edges;
            const long long* dst = src + n_edges;
            for (long long e = base8; e < nv; e += stride8) {
                #pragma unroll
                for (int q = 0; q < 8; q++) {
                    if ((int)dst[e + q] == agent) { if (k < 64) s_list[k] = (int)src[e + q]; k++; }
                }
            }
            if (bid == 0 && tid == 0)
                for (long long e = nv; e < n_edges; e++)
                    if ((int)dst[e] == agent) { if (k < 64) s_list[k] = (int)src[e]; k++; }
        } else {
            const int* src = (const int*)edges;
            const int* dst = src + n_edges;
            for (long long e = base8; e < nv; e += stride8) {
                #pragma unroll
                for (int q = 0; q < 8; q++) {
                    if (dst[e + q] == agent) { if (k < 64) s_list[k] = src[e + q]; k++; }
                }
            }
            if (bid == 0 && tid == 0)
                for (long long e = nv; e < n_edges; e++)
                    if (dst[e] == agent) { if (k < 64) s_list[k] = src[e]; k++; }
        }
    }
    __syncthreads();
    int* reg = wsi + OFF_PBM + bid * PBM_STRIDE;
    int tw = total < 64 ? total : 64;
    if (tid == 0) reg[0] = tw;
    if (tid < tw) reg[1 + tid] = s_list[tid];
}

// B: rebuild compact match list, PARALLEL deterministic hash (CAS key + min-j
// value), 8-wide degree count into line-padded DEG, export list + j->r map.
// Blocks 0..7 also L3-prefetch the needed state rows.
__global__ void __launch_bounds__(NT_B) k_B(const void* edges, const void* state,
                                            const int* agent_p,
                                            int* wsi, long long n_edges) {
    __shared__ int s_pref[NT_B];
    __shared__ int s_nodes[MAXG + 1];
    __shared__ int s_hkey[HASHN];
    __shared__ int s_hval[HASHN];
    __shared__ int s_cnt[MAXG + 1];
    __shared__ int s_i64, s_b16;
    int tid = threadIdx.x, bid = blockIdx.x;
    int i64 = detect_i64(edges, tid, &s_i64);
    bool b16 = detect_b16(state, tid, &s_b16) != 0;

    int bc = 0;
    if (tid < NB_A) {
        bc = wsi[OFF_PBM + tid * PBM_STRIDE];
        bc = bc < 64 ? (bc < 0 ? 0 : bc) : 64;
    }
    s_pref[tid] = bc;
    __syncthreads();
    #pragma unroll
    for (int off = 1; off < NT_B; off <<= 1) {
        int v = (tid >= off) ? s_pref[tid - off] : 0;
        __syncthreads();
        s_pref[tid] += v;
        __syncthreads();
    }
    int excl = s_pref[tid] - bc;
    int mc = s_pref[NT_B - 1];
    int m = mc < MAXG ? mc : MAXG;
    if (tid < NB_A) {
        for (int i = 0; i < bc; i++) {
            int g = excl + i;
            if (g < MAXG) s_nodes[1 + g] = wsi[OFF_PBM + tid * PBM_STRIDE + 1 + i];
        }
    }
    if (tid == 0) s_nodes[0] = agent_p[0];
    for (int i = tid; i < HASHN; i += NT_B) { s_hkey[i] = -1; s_hval[i] = 0x7fffffff; }
    for (int i = tid; i <= m; i += NT_B) s_cnt[i] = 0;
    __syncthreads();

    // parallel deterministic insert: CAS the key, atomicMin the value (first j).
    for (int j = tid; j <= m; j += NT_B) {
        int key = s_nodes[j];
        unsigned h = hash_n(key);
        while (true) {
            int prev = atomicCAS(&s_hkey[h], -1, key);
            if (prev == -1 || prev == key) { atomicMin(&s_hval[h], j); break; }
            h = (h + 1) & (HASHN - 1);
        }
    }
    __syncthreads();

    // blocks 0..7: L3-prefetch the m+1 needed state rows (overlaps degree count)
    if (bid < 8) {
        int esz = b16 ? 2 : 4;
        int chunks = (D_IN * esz) >> 6;   // 64B lines per row
        for (int i = tid; i < (m + 1) * chunks; i += NT_B) {
            int j = i / chunks, ch = i - j * chunks;
            long long row = s_nodes[j];
            unsigned v = *(const unsigned*)((const char*)state + row * D_IN * esz + ch * 64);
            asm volatile("" :: "v"(v));
        }
    }

    auto probe = [&](int d) {
        unsigned h = hash_n(d);
        while (true) {
            int k = s_hkey[h];
            if (k == -1) break;
            if (k == d) { atomicAdd(&s_cnt[s_hval[h]], 1); break; }
            h = (h + 1) & (HASHN - 1);
        }
    };

    long long base8 = ((long long)bid * NT_B + tid) * 8;
    const long long stride8 = (long long)NB_B * NT_B * 8;
    long long nv = n_edges & ~7LL;
    if (i64) {
        const long long* dst = (const long long*)edges + n_edges;
        for (long long e = base8; e < nv; e += stride8) {
            long2 a0 = *(const long2*)(dst + e);
            long2 a1 = *(const long2*)(dst + e + 2);
            long2 a2 = *(const long2*)(dst + e + 4);
            long2 a3 = *(const long2*)(dst + e + 6);
            probe((int)a0.x); probe((int)a0.y); probe((int)a1.x); probe((int)a1.y);
            probe((int)a2.x); probe((int)a2.y); probe((int)a3.x); probe((int)a3.y);
        }
        if (bid == 0 && tid == 0)
            for (long long e = nv; e < n_edges; e++) probe((int)dst[e]);
    } else {
        const int* dst = (const int*)edges + n_edges;
        for (long long e = base8; e < nv; e += stride8) {
            int4 a = *(const int4*)(dst + e);
            int4 b = *(const int4*)(dst + e + 4);
            probe(a.x); probe(a.y); probe(a.z); probe(a.w);
            probe(b.x); probe(b.y); probe(b.z); probe(b.w);
        }
        if (bid == 0 && tid == 0)
            for (long long e = nv; e < n_edges; e++) probe(dst[e]);
    }
    __syncthreads();
    // export: one padded cache line per representative counter
    for (int j = tid; j <= m; j += NT_B)
        if (s_cnt[j]) atomicAdd(&wsi[OFF_DEG + j * 16], s_cnt[j]);
    if (bid == 0) {
        if (tid == 0) wsi[OFF_M] = m;
        for (int i = tid; i < m; i += NT_B) wsi[OFF_CM + i] = s_nodes[1 + i];
        for (int j = tid; j <= m; j += NT_B) {
            int key = s_nodes[j];
            unsigned h = hash_n(key);
            while (s_hkey[h] != key) h = (h + 1) & (HASHN - 1);
            wsi[OFF_MAP + j] = s_hval[h];
        }
    }
}

__device__ __forceinline__ float ln256(float v, const void* lnw, const void* lnb,
                                       float* s_red, int tid, bool b16) {
    if (tid < 256) {
        float x = v;
        #pragma unroll
        for (int o = 32; o > 0; o >>= 1) x += __shfl_down(x, o);
        if ((tid & 63) == 0) s_red[tid >> 6] = x;
    }
    __syncthreads();
    float mu = (s_red[0] + s_red[1] + s_red[2] + s_red[3]) * (1.0f / 256.0f);
    if (tid < 256) {
        float dd = v - mu;
        float x = dd * dd;
        #pragma unroll
        for (int o = 32; o > 0; o >>= 1) x += __shfl_down(x, o);
        if ((tid & 63) == 0) s_red[4 + (tid >> 6)] = x;
    }
    __syncthreads();
    float var = (s_red[4] + s_red[5] + s_red[6] + s_red[7]) * (1.0f / 256.0f);
    float y = 0.0f;
    if (tid < 256)
        y = fmaxf((v - mu) * rsqrtf(var + 1e-5f) * ldf(lnw, tid, b16) + ldf(lnb, tid, b16), 0.0f);
    __syncthreads();
    return y;
}

// C: 25-block MLP pipeline, LDS-preloaded weight slices, producer-only barriers.
__global__ void __launch_bounds__(NT_C) k_C(
    const void* state, const int* agent_p,
    const void* conv_w, const void* conv_b,
    const void* fc1_w, const void* fc1_b, const void* ln1_w, const void* ln1_b,
    const void* fc2_w, const void* fc2_b, const void* ln2_w, const void* ln2_b,
    const void* mu_w, const void* mu_b,
    int* wsi, void* out)
{
    __shared__ float s_wl[8192];     // 32KB weight slice
    __shared__ float s_g[1024];      // gather scratch (8 j-groups x 128 dims)
    __shared__ float s_in[D_HID];
    __shared__ float s_part[NT_C];
    __shared__ float s_xs[D_IN];
    __shared__ float s_red[8];
    __shared__ int   s_src[MAXG];
    __shared__ float s_w[MAXG];
    __shared__ int   s_b16;

    int tid = threadIdx.x, bid = blockIdx.x;
    bool b16 = detect_b16(state, tid, &s_b16) != 0;
    float* wsf = (float*)wsi;
    int* bar = wsi + OFF_BAR;

    // ---- preload weight slice into LDS (before any waiting) ----
    if (bid < 8) {
        int o0 = bid * 32;
        for (int i = tid; i < D_IN * 32; i += NT_C)
            s_wl[i] = ldf(conv_w, (long long)(i >> 5) * D_HID + o0 + (i & 31), b16);
    } else if (bid < 16) {
        int o0 = (bid - 8) * 32;
        for (int i = tid; i < D_HID * 32; i += NT_C)
            s_wl[i] = ldf(fc1_w, (long long)(i >> 5) * D_HID + o0 + (i & 31), b16);
    } else if (bid < 24) {
        int o0 = (bid - 16) * 32;
        for (int i = tid; i < D_HID * 32; i += NT_C)
            s_wl[i] = ldf(fc2_w, (long long)(i >> 5) * D_HID + o0 + (i & 31), b16);
    } else {
        for (int i = tid; i < D_HID * 8; i += NT_C)
            s_wl[i] = ldf(mu_w, i, b16);
    }

    // ---- conv blocks 0..7: gather (8-way split) + LDS matvec -> H0 ----
    if (bid < 8) {
        int m = wsi[OFF_M];
        m = m < MAXG ? m : MAXG;
        int agent = agent_p[0];
        float dinv_a = rsqrtf((float)(ALD(&wsi[OFF_DEG]) + 1));
        for (int i = tid; i < m; i += NT_C) {
            s_src[i] = wsi[OFF_CM + i];
            int u = wsi[OFF_MAP + 1 + i];
            s_w[i] = dinv_a * rsqrtf((float)(ALD(&wsi[OFF_DEG + u * 16]) + 1));
        }
        __syncthreads();
        // 8 j-groups x 64 d-pairs (state rows L3-warm from k_B prefetch)
        int jg = tid >> 6;
        int d2 = (tid & 63) * 2;
        float a0 = 0.0f, a1 = 0.0f;
        if (jg == 0) {
            float sa, sb;
            ld2(state, (long long)agent * D_IN + d2, b16, sa, sb);
            a0 = dinv_a * dinv_a * sa;
            a1 = dinv_a * dinv_a * sb;
        }
        for (int j = jg; j < m; j += 8) {
            float sa, sb;
            ld2(state, (long long)s_src[j] * D_IN + d2, b16, sa, sb);
            float w = s_w[j];
            a0 += w * sa;
            a1 += w * sb;
        }
        s_g[jg * 128 + d2]     = a0;
        s_g[jg * 128 + d2 + 1] = a1;
        __syncthreads();
        if (tid < D_IN) {
            float acc = 0.0f;
            #pragma unroll
            for (int g = 0; g < 8; g++) acc += s_g[g * 128 + tid];
            s_xs[tid] = acc;
        }
        __syncthreads();
        int c = tid & 31, ks = tid >> 5;   // 16 k-slices of 8
        float a = 0.0f;
        #pragma unroll 8
        for (int k = ks * 8; k < ks * 8 + 8; k++)
            a += s_xs[k] * s_wl[k * 32 + c];
        s_part[tid] = a;
        __syncthreads();
        if (tid < 32) {
            int oo = bid * 32 + tid;
            float h = ldf(conv_b, oo, b16);
            #pragma unroll
            for (int s2 = 0; s2 < 16; s2++) h += s_part[s2 * 32 + tid];
            AST(&wsf[OFF_H0 + oo], fmaxf(h, 0.0f));
        }
        bar_arrive(&bar[0]);
        return;
    }

    // ---- fc1 blocks 8..15: wait conv, LDS matvec -> h1raw ----
    if (bid < 16) {
        bar_wait(&bar[0], 8);
        if (tid < D_HID) s_in[tid] = ALD(&wsf[OFF_H0 + tid]);
        __syncthreads();
        int c = tid & 31, ks = tid >> 5;   // 16 slices x 16 k
        float a = 0.0f;
        #pragma unroll 8
        for (int k = ks * 16; k < ks * 16 + 16; k++)
            a += s_in[k] * s_wl[k * 32 + c];
        s_part[tid] = a;
        __syncthreads();
        if (tid < 32) {
            int oo = (bid - 8) * 32 + tid;
            float h = ldf(fc1_b, oo, b16);
            #pragma unroll
            for (int s2 = 0; s2 < 16; s2++) h += s_part[s2 * 32 + tid];
            AST(&wsf[OFF_H1 + oo], h);
        }
        bar_arrive(&bar[1]);
        return;
    }

    // ---- fc2 blocks 16..23: wait fc1, LN1+relu inline, matvec -> h2raw ----
    if (bid < 24) {
        bar_wait(&bar[1], 8);
        float v = (tid < D_HID) ? ALD(&wsf[OFF_H1 + tid]) : 0.0f;
        float y = ln256(v, ln1_w, ln1_b, s_red, tid, b16);
        if (tid < D_HID) s_in[tid] = y;
        __syncthreads();
        int c = tid & 31, ks = tid >> 5;
        float a = 0.0f;
        #pragma unroll 8
        for (int k = ks * 16; k < ks * 16 + 16; k++)
            a += s_in[k] * s_wl[k * 32 + c];
        s_part[tid] = a;
        __syncthreads();
        if (tid < 32) {
            int oo = (bid - 16) * 32 + tid;
            float h = ldf(fc2_b, oo, b16);
            #pragma unroll
            for (int s2 = 0; s2 < 16; s2++) h += s_part[s2 * 32 + tid];
            AST(&wsf[OFF_H2 + oo], h);
        }
        bar_arrive(&bar[2]);
        return;
    }

    // ---- mu block 24: wait fc2, LN2+relu, 256x8 LDS matvec, sigmoid ----
    {
        bar_wait(&bar[2], 8);
        float v = (tid < D_HID) ? ALD(&wsf[OFF_H2 + tid]) : 0.0f;
        float y = ln256(v, ln2_w, ln2_b, s_red, tid, b16);
        if (tid < D_HID) s_in[tid] = y;
        __syncthreads();
        int o = tid & 7, ks = tid >> 3;   // 64 slices x 4 k
        float a = 0.0f;
        #pragma unroll
        for (int k = ks * 4; k < ks * 4 + 4; k++)
            a += s_in[k] * s_wl[k * 8 + o];
        s_part[tid] = a;
        __syncthreads();
        if (tid < 8) {
            float acc = ldf(mu_b, tid, b16);
            #pragma unroll
            for (int s2 = 0; s2 < 64; s2++) acc += s_part[s2 * 8 + tid];
            float r = 1.0f / (1.0f + expf(-acc));
            if (b16) ((__hip_bfloat16*)out)[tid] = __float2bfloat16(r);
            else     ((float*)out)[tid] = r;
        }
    }
}

extern "C" void kernel_launch(void* const* d_in, const int* in_sizes, int n_in,
                              void* d_out, int out_size, void* d_ws, size_t ws_size,
                              hipStream_t stream) {
    const void* state = d_in[0];
    const void* edges = d_in[1];
    const int* agent = (const int*)d_in[2];
    int* wsi = (int*)d_ws;
    long long n_edges = in_sizes[1] / 2;

    k_A<<<NB_A, NT_A, 0, stream>>>(edges, state, agent,
                                   d_in[3], d_in[5], d_in[9], d_in[13],
                                   wsi, n_edges);
    k_B<<<NB_B, NT_B, 0, stream>>>(edges, state, agent, wsi, n_edges);
    k_C<<<25, NT_C, 0, stream>>>(state, agent,
                                 d_in[3], d_in[4],
                                 d_in[5], d_in[6], d_in[7], d_in[8],
                                 d_in[9], d_in[10], d_in[11], d_in[12],
                                 d_in[13], d_in[14],
                                 wsi, d_out);
}